// Round 18
// baseline (954.304 us; speedup 1.0000x reference)
//
#include <hip/hip_runtime.h>
#include <hip/hip_bf16.h>
#include <math.h>

#define Bn 4
#define Sn 6
#define Cin 8
#define Hh 96
#define Ww 96
#define HW (Hh*Ww)          // 9216
#define Chn 64
#define Ln 13
#define LCh (Ln*Chn)        // 832
#define OC3 (3*Chn)         // 192
#define LEAK 0.2f

typedef __hip_bfloat16 bf16;
typedef __attribute__((ext_vector_type(8))) short short8v;  // 8 bf16 (4 VGPRs)
typedef __attribute__((ext_vector_type(4))) short short4v;  // 4 bf16 (8B)
typedef __attribute__((ext_vector_type(4))) float f32x4;

__device__ __forceinline__ float b2f(bf16 v){ return __bfloat162float(v); }
__device__ __forceinline__ bf16  f2b(float v){ return __float2bfloat16(v); }
__device__ __forceinline__ unsigned short bbits(bf16 v){ union{bf16 b; unsigned short s;} u; u.b=v; return u.s; }
__device__ __forceinline__ float us2f(unsigned short u){
    union{unsigned int i; float f;} x; x.i = ((unsigned)u)<<16; return x.f;
}

// bilinear meta: 4 u16 corner offsets + 4 f16 weights packed in int4
__device__ __forceinline__ int4 mk_meta(float fx, float fy, int xc, int y){
    float ix = ((float)xc - fx) * (96.0f/95.0f) - 0.5f;
    float iy = ((float)y  - fy) * (96.0f/95.0f) - 0.5f;
    float x0f = floorf(ix), y0f = floorf(iy);
    float wx1 = ix - x0f,  wy1 = iy - y0f;
    float wx0 = 1.f - wx1, wy0 = 1.f - wy1;
    float vx0 = (x0f >=  0.f && x0f <= 95.f) ? 1.f : 0.f;
    float vx1 = (x0f >= -1.f && x0f <= 94.f) ? 1.f : 0.f;
    float vy0 = (y0f >=  0.f && y0f <= 95.f) ? 1.f : 0.f;
    float vy1 = (y0f >= -1.f && y0f <= 94.f) ? 1.f : 0.f;
    int xi0 = (int)fminf(fmaxf(x0f,      0.f), 95.f);
    int xi1 = (int)fminf(fmaxf(x0f+1.f,  0.f), 95.f);
    int yi0 = (int)fminf(fmaxf(y0f,      0.f), 95.f);
    int yi1 = (int)fminf(fmaxf(y0f+1.f,  0.f), 95.f);
    union { _Float16 h[2]; int i; } pz, pw;
    pz.h[0] = (_Float16)(wx0*wy0*vx0*vy0);
    pz.h[1] = (_Float16)(wx1*wy0*vx1*vy0);
    pw.h[0] = (_Float16)(wx0*wy1*vx0*vy1);
    pw.h[1] = (_Float16)(wx1*wy1*vx1*vy1);
    int4 m;
    m.x = (yi0*Ww+xi0) | ((yi0*Ww+xi1)<<16);
    m.y = (yi1*Ww+xi0) | ((yi1*Ww+xi1)<<16);
    m.z = pz.i; m.w = pw.i;
    return m;
}

// ============ merged one-time prep: weight packs only ============
__global__ void k_prep(const float* __restrict__ fw1, const float* __restrict__ fw2,
                       const float* __restrict__ wi,  const float* __restrict__ rw,
                       bf16* __restrict__ W1b, bf16* __restrict__ W2b,
                       bf16* __restrict__ Wi,  bf16* __restrict__ Wb)
{
    int i = blockIdx.x*256 + threadIdx.x;
    if (i < 21504){                                   // W1b (32,672) k=tap*72+ic
        int oc = i/672, k = i%672; float v = 0.f;
        if (k < 648){ int tap = k/72, ic = k%72; v = fw1[(size_t)oc*648 + ic*9 + tap]; }
        W1b[i] = f2b(v);
    } else if (i < 30720){                            // W2b (32,288) k=tap*32+ic
        int j = i-21504; int oc = j/288, k = j%288; float v = 0.f;
        if (oc < 26){ int tap = k/32, ic = k%32; v = fw2[(size_t)oc*288 + ic*9 + tap]; }
        W2b[j] = f2b(v);
    } else if (i < 49152){                            // Wi (192,96) k=tap*8+ic
        int j = i-30720; int oc = j/96, k = j%96; float v = 0.f;
        if (k < 72){ int tap = k/8, ic = k%8; v = wi[(size_t)oc*72 + ic*9 + tap]; }
        Wi[j] = f2b(v);
    } else if (i < 208896){                           // Wb (192,832)
        int j = i-49152; Wb[j] = f2b(rw[j]);
    }
}

// ============ pack x (B,S,C,HW) f32 -> x_hwc (B*S, HW, 8) bf16, once ========
__global__ void k_packx(const float* __restrict__ x, bf16* __restrict__ x_hwc)
{
    __shared__ unsigned short tx[8][68];
    int bs = blockIdx.y, pix0 = blockIdx.x*64, tid = threadIdx.x;
    #pragma unroll
    for (int it=0; it<2; ++it){
        int idx = it*256 + tid, ic = idx>>6, p = idx&63;
        tx[ic][p] = bbits(f2b(x[((size_t)bs*Cin + ic)*HW + pix0 + p]));
    }
    __syncthreads();
    unsigned short* dst = (unsigned short*)x_hwc;
    #pragma unroll
    for (int it=0; it<2; ++it){
        int j = it*256 + tid, p = j>>3, c = j&7;
        dst[((size_t)bs*HW + pix0 + p)*8 + c] = tx[c][p];
    }
}

// ============ init h_hwc from states (B,64,HW) f32 -> (B,HW,64) bf16 ========
__global__ void k_packh0(const float* __restrict__ s, bf16* __restrict__ hwc)
{
    __shared__ unsigned short t[64][65];
    int b = blockIdx.y, pix0 = blockIdx.x*64, tid = threadIdx.x;
    unsigned short* dst = (unsigned short*)hwc;
    #pragma unroll
    for (int it=0; it<16; ++it){
        int idx = it*256 + tid, c = idx>>6, p = idx&63;
        t[c][p] = bbits(f2b(s[((size_t)b*Chn + c)*HW + pix0 + p]));
    }
    __syncthreads();
    #pragma unroll
    for (int it=0; it<16; ++it){
        int idx = it*256 + tid, p = idx>>6, c = idx&63;
        dst[((size_t)b*HW + pix0 + p)*Chn + c] = t[c][p];
    }
}

// ============ front: merged i2h (8->192, HWC out) + conv1 (72->32) ==========
__global__ __launch_bounds__(384) void k_front(const bf16* __restrict__ x_hwc,
        const bf16* __restrict__ h_hwc,
        const bf16* __restrict__ Wi,  const float* __restrict__ ib,
        const bf16* __restrict__ W1b, const float* __restrict__ fb1,
        bf16* __restrict__ i2h_hwc, bf16* __restrict__ f_hwc, int t)
{
    __shared__ bf16 tile[3*98*72];                   // 42336 B
    int y = blockIdx.x, b = blockIdx.y, tid = threadIdx.x;
    const bf16* xb = x_hwc + (size_t)(b*Sn + t)*HW*8;
    const bf16* hb = h_hwc + (size_t)b*HW*64;
    for (int s = tid; s < 294; s += 384){
        int r = s/98, px = s%98 - 1, yy = y + r - 1;
        float4* dst = (float4*)&tile[s*72];
        if (yy>=0 && yy<Hh && px>=0 && px<Ww){
            size_t gp = (size_t)yy*Ww + px;
            dst[0] = *(const float4*)(xb + gp*8);
            const float4* hsrc = (const float4*)(hb + gp*64);
            #pragma unroll
            for (int q=0;q<8;++q) dst[1+q] = hsrc[q];
        } else {
            float4 z{0,0,0,0};
            #pragma unroll
            for (int q=0;q<9;++q) dst[q] = z;
        }
    }
    __syncthreads();
    int wv = tid>>6, lane = tid&63, x0 = wv*16, n = lane&15, kg = lane>>4;
    int pix = y*Ww + x0 + n;

    // ---- i2h: K=96 (12 groups of 8 = x channels of each tap) ----
    {
        f32x4 acc[12];
        #pragma unroll
        for (int m=0;m<12;++m) acc[m] = f32x4{0,0,0,0};
        #pragma unroll
        for (int kk=0; kk<3; ++kk){
            int g = kk*4 + kg;                       // 0..11; valid taps 0..8
            int tap = (g > 8) ? 8 : g;               // A is zero for g>8
            int dy = tap/3, dx = tap%3;
            short8v bv = *(const short8v*)&tile[((dy*98) + (x0+n) + dx)*72];
            #pragma unroll
            for (int m=0;m<12;++m){
                short8v av = *(const short8v*)(Wi + (size_t)(m*16 + n)*96 + g*8);
                acc[m] = __builtin_amdgcn_mfma_f32_16x16x32_bf16(av, bv, acc[m], 0,0,0);
            }
        }
        size_t prow = ((size_t)b*HW + pix)*192;
        #pragma unroll
        for (int m=0;m<12;++m){
            short4v sv;
            #pragma unroll
            for (int r=0;r<4;++r){
                int oc = m*16 + kg*4 + r;
                sv[r] = (short)bbits(f2b(acc[m][r] + ib[oc]));
            }
            *(short4v*)&i2h_hwc[prow + m*16 + kg*4] = sv;
        }
    }

    // ---- conv1: K=672 (81 valid groups) ----
    {
        f32x4 acc0{0,0,0,0}, acc1{0,0,0,0};
        #pragma unroll
        for (int kk=0; kk<21; ++kk){
            int g = kk*4 + kg;                       // 0..83; valid 0..80
            int gc = (g > 80) ? 80 : g;
            int tap = gc/9, ch0 = (gc%9)*8;
            int dy = tap/3, dx = tap%3;
            short8v bv = *(const short8v*)&tile[(((dy*98) + (x0+n) + dx))*72 + ch0];
            short8v a0 = *(const short8v*)(W1b + (size_t)n*672 + g*8);
            short8v a1 = *(const short8v*)(W1b + (size_t)(16+n)*672 + g*8);
            acc0 = __builtin_amdgcn_mfma_f32_16x16x32_bf16(a0, bv, acc0, 0,0,0);
            acc1 = __builtin_amdgcn_mfma_f32_16x16x32_bf16(a1, bv, acc1, 0,0,0);
        }
        size_t prow = (size_t)b*HW + pix;
        #pragma unroll
        for (int mt=0; mt<2; ++mt){
            f32x4 a = mt ? acc1 : acc0;
            short4v sv;
            #pragma unroll
            for (int r=0;r<4;++r){
                int oc = mt*16 + kg*4 + r;
                float v = a[r] + fb1[oc];
                sv[r] = (short)bbits(f2b((v >= 0.f) ? v : LEAK*v));
            }
            *(short4v*)&f_hwc[prow*32 + mt*16 + kg*4] = sv;
        }
    }
}

// ============ conv2meta: 3x3 conv 32->26 + bilinear meta ====================
__global__ __launch_bounds__(384) void k_conv2meta(const bf16* __restrict__ f_hwc,
        const bf16* __restrict__ W2b, const float* __restrict__ fb2,
        int4* __restrict__ meta)
{
    __shared__ bf16 tile[3*98*32];                   // 18816 B
    int y = blockIdx.x, b = blockIdx.y, tid = threadIdx.x;
    const bf16* fb = f_hwc + (size_t)b*HW*32;
    for (int s = tid; s < 294; s += 384){
        int r = s/98, px = s%98 - 1, yy = y + r - 1;
        float4* dst = (float4*)&tile[s*32];
        if (yy>=0 && yy<Hh && px>=0 && px<Ww){
            const float4* src = (const float4*)(fb + ((size_t)yy*Ww + px)*32);
            #pragma unroll
            for (int q=0;q<4;++q) dst[q] = src[q];
        } else {
            float4 z{0,0,0,0};
            #pragma unroll
            for (int q=0;q<4;++q) dst[q] = z;
        }
    }
    __syncthreads();
    int wv = tid>>6, lane = tid&63, x0 = wv*16, n = lane&15, kg = lane>>4;
    f32x4 acc0{0,0,0,0}, acc1{0,0,0,0};
    #pragma unroll
    for (int kk=0; kk<9; ++kk){
        int g = kk*4 + kg;                           // 0..35, all valid
        int tap = g>>2, ch0 = (g&3)*8;
        int dy = tap/3, dx = tap%3;
        short8v bv = *(const short8v*)&tile[(((dy*98) + (x0+n) + dx))*32 + ch0];
        short8v a0 = *(const short8v*)(W2b + (size_t)n*288 + g*8);
        short8v a1 = *(const short8v*)(W2b + (size_t)(16+n)*288 + g*8);
        acc0 = __builtin_amdgcn_mfma_f32_16x16x32_bf16(a0, bv, acc0, 0,0,0);
        acc1 = __builtin_amdgcn_mfma_f32_16x16x32_bf16(a1, bv, acc1, 0,0,0);
    }
    int xc = x0 + n, pix = y*Ww + xc;
    int4* mb = meta + (size_t)b*Ln*HW + pix;
    {
        float v0 = acc0[0] + fb2[kg*4+0], v1 = acc0[1] + fb2[kg*4+1];
        float v2 = acc0[2] + fb2[kg*4+2], v3 = acc0[3] + fb2[kg*4+3];
        mb[(size_t)(2*kg  )*HW] = mk_meta(v0, v1, xc, y);
        mb[(size_t)(2*kg+1)*HW] = mk_meta(v2, v3, xc, y);
    }
    if (kg < 3){
        float v0 = acc1[0] + fb2[16+kg*4+0], v1 = acc1[1] + fb2[16+kg*4+1];
        mb[(size_t)(8+2*kg)*HW] = mk_meta(v0, v1, xc, y);
        if (kg < 2){
            float v2 = acc1[2] + fb2[16+kg*4+2], v3 = acc1[3] + fb2[16+kg*4+3];
            mb[(size_t)(9+2*kg)*HW] = mk_meta(v2, v3, xc, y);
        }
    }
}

// ============ k_fused: barrier-free, LDS-free gather->MFMA + gates ==========
// Swapped GEMM: M=pixels, N=oc. Wave = 32 px (2 M-tiles) x 96 oc (6 N-tiles:
// {nb,nb+1,nb+4,nb+5,nb+8,nb+9}, nb=wv*2 -> gate triplets lane-local).
// A-fragment for K-step kk = warped[px=lane&15][kk*32+(lane>>4)*8..+8],
// computed in-register from 4 corner dwordx4 gathers. B = Wb rows (L2-hot).
// D: row=(lane>>4)*4+r = px-within-tile, col=lane&15 = oc-within-tile.
__global__ __launch_bounds__(128) void k_fused(const int4* __restrict__ meta,
        const bf16* __restrict__ h_cur, const bf16* __restrict__ Wb,
        const float* __restrict__ rb, const bf16* __restrict__ i2h_hwc,
        bf16* __restrict__ h_nxt, float* __restrict__ out, int t)
{
    int tid = threadIdx.x, wv = tid>>6, lane = tid&63;
    int b = blockIdx.y, pix0 = blockIdx.x*32;
    int col = lane & 15, kg = lane >> 4;
    int nb = wv*2;
    const bf16* hb = h_cur + (size_t)b*HW*64;
    const unsigned short* hsu = (const unsigned short*)hb;
    const int4* mb = meta + (size_t)b*Ln*HW + pix0;

    // B row pointers for the 6 oc tiles (include kg*8 K-offset)
    const bf16* brow0 = Wb + (size_t)((nb+0)*16 + col)*LCh + kg*8;
    const bf16* brow1 = Wb + (size_t)((nb+1)*16 + col)*LCh + kg*8;
    const bf16* brow2 = Wb + (size_t)((nb+4)*16 + col)*LCh + kg*8;
    const bf16* brow3 = Wb + (size_t)((nb+5)*16 + col)*LCh + kg*8;
    const bf16* brow4 = Wb + (size_t)((nb+8)*16 + col)*LCh + kg*8;
    const bf16* brow5 = Wb + (size_t)((nb+9)*16 + col)*LCh + kg*8;

    f32x4 acc[2][6];
    #pragma unroll
    for (int m=0;m<2;++m)
        #pragma unroll
        for (int j=0;j<6;++j) acc[m][j] = f32x4{0,0,0,0};

    #pragma unroll
    for (int kk=0; kk<26; ++kk){
        int l = kk>>1;
        int c0 = (kk&1)*32 + kg*8;                   // channel base of this octet
        short8v af0, af1;
        #pragma unroll
        for (int m=0;m<2;++m){
            int4 mm = mb[(size_t)l*HW + m*16 + col];
            int o00 = mm.x & 0xFFFF, o10 = ((unsigned)mm.x) >> 16;
            int o01 = mm.y & 0xFFFF, o11 = ((unsigned)mm.y) >> 16;
            union { int i; _Float16 h[2]; } uz, uw;
            uz.i = mm.z; uw.i = mm.w;
            float w00 = (float)uz.h[0], w10 = (float)uz.h[1];
            float w01 = (float)uw.h[0], w11 = (float)uw.h[1];
            short8v v00 = *(const short8v*)(hsu + (size_t)o00*64 + c0);
            short8v v10 = *(const short8v*)(hsu + (size_t)o10*64 + c0);
            short8v v01 = *(const short8v*)(hsu + (size_t)o01*64 + c0);
            short8v v11 = *(const short8v*)(hsu + (size_t)o11*64 + c0);
            short8v r8;
            #pragma unroll
            for (int k=0;k<8;++k){
                float v = us2f((unsigned short)v00[k])*w00
                        + us2f((unsigned short)v10[k])*w10
                        + us2f((unsigned short)v01[k])*w01
                        + us2f((unsigned short)v11[k])*w11;
                r8[k] = (short)bbits(f2b(v));
            }
            if (m == 0) af0 = r8; else af1 = r8;
        }
        short8v bf0 = *(const short8v*)(brow0 + kk*32);
        short8v bf1 = *(const short8v*)(brow1 + kk*32);
        short8v bf2 = *(const short8v*)(brow2 + kk*32);
        short8v bf3 = *(const short8v*)(brow3 + kk*32);
        short8v bf4 = *(const short8v*)(brow4 + kk*32);
        short8v bf5 = *(const short8v*)(brow5 + kk*32);
        acc[0][0] = __builtin_amdgcn_mfma_f32_16x16x32_bf16(af0, bf0, acc[0][0], 0,0,0);
        acc[0][1] = __builtin_amdgcn_mfma_f32_16x16x32_bf16(af0, bf1, acc[0][1], 0,0,0);
        acc[0][2] = __builtin_amdgcn_mfma_f32_16x16x32_bf16(af0, bf2, acc[0][2], 0,0,0);
        acc[0][3] = __builtin_amdgcn_mfma_f32_16x16x32_bf16(af0, bf3, acc[0][3], 0,0,0);
        acc[0][4] = __builtin_amdgcn_mfma_f32_16x16x32_bf16(af0, bf4, acc[0][4], 0,0,0);
        acc[0][5] = __builtin_amdgcn_mfma_f32_16x16x32_bf16(af0, bf5, acc[0][5], 0,0,0);
        acc[1][0] = __builtin_amdgcn_mfma_f32_16x16x32_bf16(af1, bf0, acc[1][0], 0,0,0);
        acc[1][1] = __builtin_amdgcn_mfma_f32_16x16x32_bf16(af1, bf1, acc[1][1], 0,0,0);
        acc[1][2] = __builtin_amdgcn_mfma_f32_16x16x32_bf16(af1, bf2, acc[1][2], 0,0,0);
        acc[1][3] = __builtin_amdgcn_mfma_f32_16x16x32_bf16(af1, bf3, acc[1][3], 0,0,0);
        acc[1][4] = __builtin_amdgcn_mfma_f32_16x16x32_bf16(af1, bf4, acc[1][4], 0,0,0);
        acc[1][5] = __builtin_amdgcn_mfma_f32_16x16x32_bf16(af1, bf5, acc[1][5], 0,0,0);
    }

    // ---- gates: lane-local triplets; float4 out stores ----
    #pragma unroll
    for (int m=0;m<2;++m){
        int pxbase = pix0 + m*16 + kg*4;
        #pragma unroll
        for (int jn=0;jn<2;++jn){
            int cc = (nb+jn)*16 + col;
            float rbias1 = rb[cc], rbias2 = rb[cc+64], rbias3 = rb[cc+128];
            float4 ov;
            #pragma unroll
            for (int r=0;r<4;++r){
                int px = pxbase + r;
                float h1 = acc[m][jn  ][r] + rbias1;
                float h2 = acc[m][jn+2][r] + rbias2;
                float h3 = acc[m][jn+4][r] + rbias3;
                const unsigned short* ip = (const unsigned short*)
                    (i2h_hwc + ((size_t)b*HW + px)*192 + cc);
                float i1 = us2f(ip[0]);
                float i2 = us2f(ip[64]);
                float i3 = us2f(ip[128]);
                float hv = us2f(((const unsigned short*)hb)[(size_t)px*64 + cc]);
                float rg = 1.f/(1.f + expf(-(i1 + h1)));
                float u  = 1.f/(1.f + expf(-(i2 + h2)));
                float mp = i3 + rg*h3;
                float mm2 = (mp >= 0.f) ? mp : LEAK*mp;
                float nh = u*hv + (1.f - u)*mm2;
                ((float*)&ov)[r] = nh;
                h_nxt[((size_t)b*HW + px)*64 + cc] = f2b(nh);
            }
            *(float4*)&out[(((size_t)(b*Sn+t))*Chn + cc)*HW + pxbase] = ov;
            if (t == Sn-1)
                *(float4*)&out[(size_t)Bn*Sn*Chn*HW
                               + ((size_t)b*Chn + cc)*HW + pxbase] = ov;
        }
    }
}

extern "C" void kernel_launch(void* const* d_in, const int* in_sizes, int n_in,
                              void* d_out, int out_size, void* d_ws, size_t ws_size,
                              hipStream_t stream) {
    const float* inputs = (const float*)d_in[0];
    const float* states = (const float*)d_in[1];
    const float* fw1    = (const float*)d_in[2];
    const float* fb1    = (const float*)d_in[3];
    const float* fw2    = (const float*)d_in[4];
    const float* fb2    = (const float*)d_in[5];
    const float* i2h_w  = (const float*)d_in[6];
    const float* i2h_b  = (const float*)d_in[7];
    const float* ret_w  = (const float*)d_in[8];
    const float* ret_b  = (const float*)d_in[9];
    float* out = (float*)d_out;

    // ws layout (bytes), total ~37.6 MB (< 59.3 MB proven safe)
    char* ws = (char*)d_ws;
    bf16* h_hwcA  = (bf16*)(ws);                     //  4,718,592  (B,HW,64)
    bf16* h_hwcB  = (bf16*)(ws +  4718592);          //  4,718,592  (B,HW,64)
    bf16* x_hwc   = (bf16*)(ws +  9437184);          //  3,538,944  (B*S,HW,8)
    bf16* i2h_hwc = (bf16*)(ws + 12976128);          // 14,155,776  (B,HW,192)
    bf16* f_hwc   = (bf16*)(ws + 27131904);          //  2,359,296  (B,HW,32)
    int4* meta    = (int4*)(ws + 29491200);          //  7,667,712  (B,13,HW) int4
    bf16* W1b     = (bf16*)(ws + 37158912);          //     43,008  (32,672)
    bf16* W2b     = (bf16*)(ws + 37201920);          //     18,432  (32,288)
    bf16* Wi      = (bf16*)(ws + 37220352);          //     36,864  (192,96)
    bf16* Wb      = (bf16*)(ws + 37257216);          //    319,488  (192,832)

    k_prep  <<<dim3(816),        256, 0, stream>>>(fw1, fw2, i2h_w, ret_w,
                                                   W1b, W2b, Wi, Wb);
    k_packx <<<dim3(144, Bn*Sn), 256, 0, stream>>>(inputs, x_hwc);
    k_packh0<<<dim3(144, Bn),    256, 0, stream>>>(states, h_hwcA);

    bf16* h_cur = h_hwcA;
    bf16* h_nxt = h_hwcB;
    for (int t = 0; t < Sn; ++t) {
        k_front    <<<dim3(96, Bn),  384, 0, stream>>>(x_hwc, h_cur, Wi, i2h_b,
                                                       W1b, fb1, i2h_hwc, f_hwc, t);
        k_conv2meta<<<dim3(96, Bn),  384, 0, stream>>>(f_hwc, W2b, fb2, meta);
        k_fused    <<<dim3(288, Bn), 128, 0, stream>>>(meta, h_cur, Wb, ret_b,
                                                       i2h_hwc, h_nxt, out, t);
        bf16* tmp = h_cur; h_cur = h_nxt; h_nxt = tmp;
    }
}

// Round 19
// 695.224 us; speedup vs baseline: 1.3727x; 1.3727x over previous
//
#include <hip/hip_runtime.h>
#include <hip/hip_bf16.h>
#include <math.h>

#define Bn 4
#define Sn 6
#define Cin 8
#define Hh 96
#define Ww 96
#define HW (Hh*Ww)          // 9216
#define Chn 64
#define Ln 13
#define LCh (Ln*Chn)        // 832
#define OC3 (3*Chn)         // 192
#define LEAK 0.2f

typedef __hip_bfloat16 bf16;
typedef __attribute__((ext_vector_type(8))) short short8v;  // 8 bf16 (4 VGPRs)
typedef __attribute__((ext_vector_type(4))) short short4v;  // 4 bf16 (8B)
typedef __attribute__((ext_vector_type(4))) float f32x4;

__device__ __forceinline__ float b2f(bf16 v){ return __bfloat162float(v); }
__device__ __forceinline__ bf16  f2b(float v){ return __float2bfloat16(v); }
__device__ __forceinline__ unsigned short bbits(bf16 v){ union{bf16 b; unsigned short s;} u; u.b=v; return u.s; }
__device__ __forceinline__ float us2f(unsigned short u){
    union{unsigned int i; float f;} x; x.i = ((unsigned)u)<<16; return x.f;
}

// bilinear meta: 4 u16 corner offsets + 4 f16 weights packed in int4
__device__ __forceinline__ int4 mk_meta(float fx, float fy, int xc, int y){
    float ix = ((float)xc - fx) * (96.0f/95.0f) - 0.5f;
    float iy = ((float)y  - fy) * (96.0f/95.0f) - 0.5f;
    float x0f = floorf(ix), y0f = floorf(iy);
    float wx1 = ix - x0f,  wy1 = iy - y0f;
    float wx0 = 1.f - wx1, wy0 = 1.f - wy1;
    float vx0 = (x0f >=  0.f && x0f <= 95.f) ? 1.f : 0.f;
    float vx1 = (x0f >= -1.f && x0f <= 94.f) ? 1.f : 0.f;
    float vy0 = (y0f >=  0.f && y0f <= 95.f) ? 1.f : 0.f;
    float vy1 = (y0f >= -1.f && y0f <= 94.f) ? 1.f : 0.f;
    int xi0 = (int)fminf(fmaxf(x0f,      0.f), 95.f);
    int xi1 = (int)fminf(fmaxf(x0f+1.f,  0.f), 95.f);
    int yi0 = (int)fminf(fmaxf(y0f,      0.f), 95.f);
    int yi1 = (int)fminf(fmaxf(y0f+1.f,  0.f), 95.f);
    union { _Float16 h[2]; int i; } pz, pw;
    pz.h[0] = (_Float16)(wx0*wy0*vx0*vy0);
    pz.h[1] = (_Float16)(wx1*wy0*vx1*vy0);
    pw.h[0] = (_Float16)(wx0*wy1*vx0*vy1);
    pw.h[1] = (_Float16)(wx1*wy1*vx1*vy1);
    int4 m;
    m.x = (yi0*Ww+xi0) | ((yi0*Ww+xi1)<<16);
    m.y = (yi1*Ww+xi0) | ((yi1*Ww+xi1)<<16);
    m.z = pz.i; m.w = pw.i;
    return m;
}

// ============ merged one-time prep: weight packs only ============
__global__ void k_prep(const float* __restrict__ fw1, const float* __restrict__ fw2,
                       const float* __restrict__ wi,  const float* __restrict__ rw,
                       bf16* __restrict__ W1b, bf16* __restrict__ W2b,
                       bf16* __restrict__ Wi,  bf16* __restrict__ Wb)
{
    int i = blockIdx.x*256 + threadIdx.x;
    if (i < 21504){                                   // W1b (32,672) k=tap*72+ic
        int oc = i/672, k = i%672; float v = 0.f;
        if (k < 648){ int tap = k/72, ic = k%72; v = fw1[(size_t)oc*648 + ic*9 + tap]; }
        W1b[i] = f2b(v);
    } else if (i < 30720){                            // W2b (32,288) k=tap*32+ic
        int j = i-21504; int oc = j/288, k = j%288; float v = 0.f;
        if (oc < 26){ int tap = k/32, ic = k%32; v = fw2[(size_t)oc*288 + ic*9 + tap]; }
        W2b[j] = f2b(v);
    } else if (i < 49152){                            // Wi (192,96) k=tap*8+ic
        int j = i-30720; int oc = j/96, k = j%96; float v = 0.f;
        if (k < 72){ int tap = k/8, ic = k%8; v = wi[(size_t)oc*72 + ic*9 + tap]; }
        Wi[j] = f2b(v);
    } else if (i < 208896){                           // Wb (192,832)
        int j = i-49152; Wb[j] = f2b(rw[j]);
    }
}

// ============ pack x (B,S,C,HW) f32 -> x_hwc (B*S, HW, 8) bf16, once ========
__global__ void k_packx(const float* __restrict__ x, bf16* __restrict__ x_hwc)
{
    __shared__ unsigned short tx[8][68];
    int bs = blockIdx.y, pix0 = blockIdx.x*64, tid = threadIdx.x;
    #pragma unroll
    for (int it=0; it<2; ++it){
        int idx = it*256 + tid, ic = idx>>6, p = idx&63;
        tx[ic][p] = bbits(f2b(x[((size_t)bs*Cin + ic)*HW + pix0 + p]));
    }
    __syncthreads();
    unsigned short* dst = (unsigned short*)x_hwc;
    #pragma unroll
    for (int it=0; it<2; ++it){
        int j = it*256 + tid, p = j>>3, c = j&7;
        dst[((size_t)bs*HW + pix0 + p)*8 + c] = tx[c][p];
    }
}

// ============ init h_hwc from states (B,64,HW) f32 -> (B,HW,64) bf16 ========
__global__ void k_packh0(const float* __restrict__ s, bf16* __restrict__ hwc)
{
    __shared__ unsigned short t[64][65];
    int b = blockIdx.y, pix0 = blockIdx.x*64, tid = threadIdx.x;
    unsigned short* dst = (unsigned short*)hwc;
    #pragma unroll
    for (int it=0; it<16; ++it){
        int idx = it*256 + tid, c = idx>>6, p = idx&63;
        t[c][p] = bbits(f2b(s[((size_t)b*Chn + c)*HW + pix0 + p]));
    }
    __syncthreads();
    #pragma unroll
    for (int it=0; it<16; ++it){
        int idx = it*256 + tid, p = idx>>6, c = idx&63;
        dst[((size_t)b*HW + pix0 + p)*Chn + c] = t[c][p];
    }
}

// ============ front: merged i2h (8->192, HWC out) + conv1 (72->32) ==========
// blockIdx.x XCD-swizzled: rows [12c,12c+12) -> XCD c (aligns with k_fused).
__global__ __launch_bounds__(384) void k_front(const bf16* __restrict__ x_hwc,
        const bf16* __restrict__ h_hwc,
        const bf16* __restrict__ Wi,  const float* __restrict__ ib,
        const bf16* __restrict__ W1b, const float* __restrict__ fb1,
        bf16* __restrict__ i2h_hwc, bf16* __restrict__ f_hwc, int t)
{
    __shared__ bf16 tile[3*98*72];                   // 42336 B
    int r_ = blockIdx.x;
    int y = (r_&7)*12 + (r_>>3);                     // XCD-chunked row
    int b = blockIdx.y, tid = threadIdx.x;
    const bf16* xb = x_hwc + (size_t)(b*Sn + t)*HW*8;
    const bf16* hb = h_hwc + (size_t)b*HW*64;
    for (int s = tid; s < 294; s += 384){
        int r = s/98, px = s%98 - 1, yy = y + r - 1;
        float4* dst = (float4*)&tile[s*72];
        if (yy>=0 && yy<Hh && px>=0 && px<Ww){
            size_t gp = (size_t)yy*Ww + px;
            dst[0] = *(const float4*)(xb + gp*8);
            const float4* hsrc = (const float4*)(hb + gp*64);
            #pragma unroll
            for (int q=0;q<8;++q) dst[1+q] = hsrc[q];
        } else {
            float4 z{0,0,0,0};
            #pragma unroll
            for (int q=0;q<9;++q) dst[q] = z;
        }
    }
    __syncthreads();
    int wv = tid>>6, lane = tid&63, x0 = wv*16, n = lane&15, kg = lane>>4;
    int pix = y*Ww + x0 + n;

    // ---- i2h: K=96 (12 groups of 8 = x channels of each tap) ----
    {
        f32x4 acc[12];
        #pragma unroll
        for (int m=0;m<12;++m) acc[m] = f32x4{0,0,0,0};
        #pragma unroll
        for (int kk=0; kk<3; ++kk){
            int g = kk*4 + kg;                       // 0..11; valid taps 0..8
            int tap = (g > 8) ? 8 : g;               // A is zero for g>8
            int dy = tap/3, dx = tap%3;
            short8v bv = *(const short8v*)&tile[((dy*98) + (x0+n) + dx)*72];
            #pragma unroll
            for (int m=0;m<12;++m){
                short8v av = *(const short8v*)(Wi + (size_t)(m*16 + n)*96 + g*8);
                acc[m] = __builtin_amdgcn_mfma_f32_16x16x32_bf16(av, bv, acc[m], 0,0,0);
            }
        }
        size_t prow = ((size_t)b*HW + pix)*192;
        #pragma unroll
        for (int m=0;m<12;++m){
            short4v sv;
            #pragma unroll
            for (int r=0;r<4;++r){
                int oc = m*16 + kg*4 + r;
                sv[r] = (short)bbits(f2b(acc[m][r] + ib[oc]));
            }
            *(short4v*)&i2h_hwc[prow + m*16 + kg*4] = sv;
        }
    }

    // ---- conv1: K=672 (81 valid groups) ----
    {
        f32x4 acc0{0,0,0,0}, acc1{0,0,0,0};
        #pragma unroll
        for (int kk=0; kk<21; ++kk){
            int g = kk*4 + kg;                       // 0..83; valid 0..80
            int gc = (g > 80) ? 80 : g;
            int tap = gc/9, ch0 = (gc%9)*8;
            int dy = tap/3, dx = tap%3;
            short8v bv = *(const short8v*)&tile[(((dy*98) + (x0+n) + dx))*72 + ch0];
            short8v a0 = *(const short8v*)(W1b + (size_t)n*672 + g*8);
            short8v a1 = *(const short8v*)(W1b + (size_t)(16+n)*672 + g*8);
            acc0 = __builtin_amdgcn_mfma_f32_16x16x32_bf16(a0, bv, acc0, 0,0,0);
            acc1 = __builtin_amdgcn_mfma_f32_16x16x32_bf16(a1, bv, acc1, 0,0,0);
        }
        size_t prow = (size_t)b*HW + pix;
        #pragma unroll
        for (int mt=0; mt<2; ++mt){
            f32x4 a = mt ? acc1 : acc0;
            short4v sv;
            #pragma unroll
            for (int r=0;r<4;++r){
                int oc = mt*16 + kg*4 + r;
                float v = a[r] + fb1[oc];
                sv[r] = (short)bbits(f2b((v >= 0.f) ? v : LEAK*v));
            }
            *(short4v*)&f_hwc[prow*32 + mt*16 + kg*4] = sv;
        }
    }
}

// ============ conv2meta: 3x3 conv 32->26 + bilinear meta ====================
// Same XCD-chunked row mapping as k_front.
__global__ __launch_bounds__(384) void k_conv2meta(const bf16* __restrict__ f_hwc,
        const bf16* __restrict__ W2b, const float* __restrict__ fb2,
        int4* __restrict__ meta)
{
    __shared__ bf16 tile[3*98*32];                   // 18816 B
    int r_ = blockIdx.x;
    int y = (r_&7)*12 + (r_>>3);                     // XCD-chunked row
    int b = blockIdx.y, tid = threadIdx.x;
    const bf16* fb = f_hwc + (size_t)b*HW*32;
    for (int s = tid; s < 294; s += 384){
        int r = s/98, px = s%98 - 1, yy = y + r - 1;
        float4* dst = (float4*)&tile[s*32];
        if (yy>=0 && yy<Hh && px>=0 && px<Ww){
            const float4* src = (const float4*)(fb + ((size_t)yy*Ww + px)*32);
            #pragma unroll
            for (int q=0;q<4;++q) dst[q] = src[q];
        } else {
            float4 z{0,0,0,0};
            #pragma unroll
            for (int q=0;q<4;++q) dst[q] = z;
        }
    }
    __syncthreads();
    int wv = tid>>6, lane = tid&63, x0 = wv*16, n = lane&15, kg = lane>>4;
    f32x4 acc0{0,0,0,0}, acc1{0,0,0,0};
    #pragma unroll
    for (int kk=0; kk<9; ++kk){
        int g = kk*4 + kg;                           // 0..35, all valid
        int tap = g>>2, ch0 = (g&3)*8;
        int dy = tap/3, dx = tap%3;
        short8v bv = *(const short8v*)&tile[(((dy*98) + (x0+n) + dx))*32 + ch0];
        short8v a0 = *(const short8v*)(W2b + (size_t)n*288 + g*8);
        short8v a1 = *(const short8v*)(W2b + (size_t)(16+n)*288 + g*8);
        acc0 = __builtin_amdgcn_mfma_f32_16x16x32_bf16(a0, bv, acc0, 0,0,0);
        acc1 = __builtin_amdgcn_mfma_f32_16x16x32_bf16(a1, bv, acc1, 0,0,0);
    }
    int xc = x0 + n, pix = y*Ww + xc;
    int4* mb = meta + (size_t)b*Ln*HW + pix;
    {
        float v0 = acc0[0] + fb2[kg*4+0], v1 = acc0[1] + fb2[kg*4+1];
        float v2 = acc0[2] + fb2[kg*4+2], v3 = acc0[3] + fb2[kg*4+3];
        mb[(size_t)(2*kg  )*HW] = mk_meta(v0, v1, xc, y);
        mb[(size_t)(2*kg+1)*HW] = mk_meta(v2, v3, xc, y);
    }
    if (kg < 3){
        float v0 = acc1[0] + fb2[16+kg*4+0], v1 = acc1[1] + fb2[16+kg*4+1];
        mb[(size_t)(8+2*kg)*HW] = mk_meta(v0, v1, xc, y);
        if (kg < 2){
            float v2 = acc1[2] + fb2[16+kg*4+2], v3 = acc1[3] + fb2[16+kg*4+3];
            mb[(size_t)(9+2*kg)*HW] = mk_meta(v2, v3, xc, y);
        }
    }
}

// one l-slice of the transposed gather: 16 burst loads, then FMA+ds_write
#define PROC_L(M, L)                                                      \
    {                                                                     \
        int o00 = M.x & 0xFFFF, o10 = ((unsigned)M.x) >> 16;              \
        int o01 = M.y & 0xFFFF, o11 = ((unsigned)M.y) >> 16;              \
        union { int i; _Float16 h[2]; } uz, uw;                           \
        uz.i = M.z; uw.i = M.w;                                           \
        float w00 = (float)uz.h[0], w10 = (float)uz.h[1];                 \
        float w01 = (float)uw.h[0], w11 = (float)uw.h[1];                 \
        short8v v00[4], v10[4], v01[4], v11[4];                           \
        _Pragma("unroll")                                                 \
        for (int o2=0;o2<4;++o2){                                         \
            int oct = o2*2 + oh;                                          \
            v00[o2] = *(const short8v*)(hsu + (size_t)o00*64 + oct*8);    \
            v10[o2] = *(const short8v*)(hsu + (size_t)o10*64 + oct*8);    \
            v01[o2] = *(const short8v*)(hsu + (size_t)o01*64 + oct*8);    \
            v11[o2] = *(const short8v*)(hsu + (size_t)o11*64 + oct*8);    \
        }                                                                 \
        _Pragma("unroll")                                                 \
        for (int o2=0;o2<4;++o2){                                         \
            int oct = o2*2 + oh;                                          \
            short8v r8;                                                   \
            _Pragma("unroll")                                             \
            for (int k=0;k<8;++k){                                        \
                float v = us2f((unsigned short)v00[o2][k])*w00            \
                        + us2f((unsigned short)v10[o2][k])*w10            \
                        + us2f((unsigned short)v01[o2][k])*w01            \
                        + us2f((unsigned short)v11[o2][k])*w11;           \
                r8[k] = (short)bbits(f2b(v));                             \
            }                                                             \
            *(short8v*)(ldsb + px*1664 + (((L)*128 + oct*16) ^ pswz)) = r8; \
        }                                                                 \
    }

// ============ fused warp + h2h MFMA + gates, 32 px/block ====================
// blockIdx.x XCD-swizzled: px chunks [36c*32, ...) -> XCD c, matching
// k_front/conv2meta row chunks -> gathers (local neighborhoods) hit the
// local XCD's L2 instead of a ~900cy cross-XCD L3 round trip.
__global__ __launch_bounds__(256) void k_fused(const int4* __restrict__ meta,
        const bf16* __restrict__ h_cur, const bf16* __restrict__ Wb,
        const float* __restrict__ rb, const bf16* __restrict__ i2h_hwc,
        bf16* __restrict__ h_nxt, float* __restrict__ out, int t)
{
    __shared__ bf16 wlds[32*LCh];                    // 53248 B
    char* ldsb = (char*)wlds;
    int tid = threadIdx.x, wv = tid>>6, lane = tid&63;
    int r_ = blockIdx.x;
    int bx = (r_&7)*36 + (r_>>3);                    // XCD-chunked px block
    int b = blockIdx.y, pix0 = bx*32;
    const bf16* hb = h_cur + (size_t)b*HW*64;
    const unsigned short* hsu = (const unsigned short*)hb;
    const int4* mb = meta + (size_t)b*Ln*HW + pix0;

    // ---- gate-input prefetch: issue FIRST (overlaps entire gather) ----
    int col = lane & 15, kg = lane >> 4;
    int pxa = pix0 + col, pxb = pxa + 16;
    short4v hva = *(const short4v*)&hb[(size_t)pxa*64 + wv*16 + kg*4];
    short4v hvb = *(const short4v*)&hb[(size_t)pxb*64 + wv*16 + kg*4];
    const bf16* ia = i2h_hwc + ((size_t)b*HW + pxa)*192 + wv*16 + kg*4;
    const bf16* ibp= i2h_hwc + ((size_t)b*HW + pxb)*192 + wv*16 + kg*4;
    short4v i1a = *(const short4v*)(ia);
    short4v i2a = *(const short4v*)(ia + 64);
    short4v i3a = *(const short4v*)(ia + 128);
    short4v i1b = *(const short4v*)(ibp);
    short4v i2b = *(const short4v*)(ibp + 64);
    short4v i3b = *(const short4v*)(ibp + 128);

    // ---- phase 1: meta prefetch, then burst gathers ----
    int px = lane & 31, oh = lane >> 5;
    int pswz = (px&7)<<4;
    int4 m0 = mb[(size_t)(wv+0)*HW + px];
    int4 m1 = mb[(size_t)(wv+4)*HW + px];
    int4 m2 = mb[(size_t)(wv+8)*HW + px];
    int4 m3 = (wv == 0) ? mb[(size_t)12*HW + px] : m2;

    PROC_L(m0, (wv+0));
    PROC_L(m1, (wv+4));
    PROC_L(m2, (wv+8));
    if (wv == 0) PROC_L(m3, 12);
    __syncthreads();

    // ---- phase 2: C[192,32] = Wb[192,832] x warped_lds[832,32] ----
    const short8v* a0 = (const short8v*)(Wb + (size_t)((wv+0)*16+col)*LCh + kg*8);
    const short8v* a1 = (const short8v*)(Wb + (size_t)((wv+4)*16+col)*LCh + kg*8);
    const short8v* a2 = (const short8v*)(Wb + (size_t)((wv+8)*16+col)*LCh + kg*8);
    f32x4 c0a{0,0,0,0}, c1a{0,0,0,0}, c2a{0,0,0,0};
    f32x4 c0b{0,0,0,0}, c1b{0,0,0,0}, c2b{0,0,0,0};
    int swz = (col&7)<<4;
    short8v pa0 = a0[0], pa1 = a1[0], pa2 = a2[0];
    #pragma unroll
    for (int kk=0; kk<26; ++kk){
        short8v na0 = pa0, na1 = pa1, na2 = pa2;
        if (kk < 25){
            na0 = a0[(kk+1)*4]; na1 = a1[(kk+1)*4]; na2 = a2[(kk+1)*4];
        }
        int offa = col*1664 + ((kk*64 + kg*16) ^ swz);
        int offb = (col+16)*1664 + ((kk*64 + kg*16) ^ swz);
        short8v bva = *(const short8v*)(ldsb + offa);
        short8v bvb = *(const short8v*)(ldsb + offb);
        c0a = __builtin_amdgcn_mfma_f32_16x16x32_bf16(pa0, bva, c0a, 0,0,0);
        c0b = __builtin_amdgcn_mfma_f32_16x16x32_bf16(pa0, bvb, c0b, 0,0,0);
        c1a = __builtin_amdgcn_mfma_f32_16x16x32_bf16(pa1, bva, c1a, 0,0,0);
        c1b = __builtin_amdgcn_mfma_f32_16x16x32_bf16(pa1, bvb, c1b, 0,0,0);
        c2a = __builtin_amdgcn_mfma_f32_16x16x32_bf16(pa2, bva, c2a, 0,0,0);
        c2b = __builtin_amdgcn_mfma_f32_16x16x32_bf16(pa2, bvb, c2b, 0,0,0);
        pa0 = na0; pa1 = na1; pa2 = na2;
    }

    // ---- phase 3: GRU gates; direct h_nxt stores (own 4-ch chunk, 8B) ----
    float nha[4], nhb[4];
    #pragma unroll
    for (int r=0; r<4; ++r){
        int cc = wv*16 + kg*4 + r;
        float h1 = c0a[r] + rb[cc];
        float h2 = c1a[r] + rb[cc+64];
        float h3 = c2a[r] + rb[cc+128];
        float rg = 1.f/(1.f + expf(-(us2f((unsigned short)i1a[r]) + h1)));
        float u  = 1.f/(1.f + expf(-(us2f((unsigned short)i2a[r]) + h2)));
        float mp = us2f((unsigned short)i3a[r]) + rg*h3;
        float m  = (mp >= 0.f) ? mp : LEAK*mp;
        float nh = u*us2f((unsigned short)hva[r]) + (1.f - u)*m;
        nha[r] = nh;
        out[(((size_t)(b*Sn+t))*Chn + cc)*HW + pxa] = nh;
        if (t == Sn-1)
            out[(size_t)Bn*Sn*Chn*HW + ((size_t)b*Chn + cc)*HW + pxa] = nh;
    }
    #pragma unroll
    for (int r=0; r<4; ++r){
        int cc = wv*16 + kg*4 + r;
        float h1 = c0b[r] + rb[cc];
        float h2 = c1b[r] + rb[cc+64];
        float h3 = c2b[r] + rb[cc+128];
        float rg = 1.f/(1.f + expf(-(us2f((unsigned short)i1b[r]) + h1)));
        float u  = 1.f/(1.f + expf(-(us2f((unsigned short)i2b[r]) + h2)));
        float mp = us2f((unsigned short)i3b[r]) + rg*h3;
        float m  = (mp >= 0.f) ? mp : LEAK*mp;
        float nh = u*us2f((unsigned short)hvb[r]) + (1.f - u)*m;
        nhb[r] = nh;
        out[(((size_t)(b*Sn+t))*Chn + cc)*HW + pxb] = nh;
        if (t == Sn-1)
            out[(size_t)Bn*Sn*Chn*HW + ((size_t)b*Chn + cc)*HW + pxb] = nh;
    }
    short4v sva, svb;
    #pragma unroll
    for (int r=0; r<4; ++r){
        sva[r] = (short)bbits(f2b(nha[r]));
        svb[r] = (short)bbits(f2b(nhb[r]));
    }
    *(short4v*)&h_nxt[((size_t)b*HW + pxa)*64 + wv*16 + kg*4] = sva;
    *(short4v*)&h_nxt[((size_t)b*HW + pxb)*64 + wv*16 + kg*4] = svb;
}

extern "C" void kernel_launch(void* const* d_in, const int* in_sizes, int n_in,
                              void* d_out, int out_size, void* d_ws, size_t ws_size,
                              hipStream_t stream) {
    const float* inputs = (const float*)d_in[0];
    const float* states = (const float*)d_in[1];
    const float* fw1    = (const float*)d_in[2];
    const float* fb1    = (const float*)d_in[3];
    const float* fw2    = (const float*)d_in[4];
    const float* fb2    = (const float*)d_in[5];
    const float* i2h_w  = (const float*)d_in[6];
    const float* i2h_b  = (const float*)d_in[7];
    const float* ret_w  = (const float*)d_in[8];
    const float* ret_b  = (const float*)d_in[9];
    float* out = (float*)d_out;

    // ws layout (bytes), total ~37.6 MB (< 59.3 MB proven safe)
    char* ws = (char*)d_ws;
    bf16* h_hwcA  = (bf16*)(ws);                     //  4,718,592  (B,HW,64)
    bf16* h_hwcB  = (bf16*)(ws +  4718592);          //  4,718,592  (B,HW,64)
    bf16* x_hwc   = (bf16*)(ws +  9437184);          //  3,538,944  (B*S,HW,8)
    bf16* i2h_hwc = (bf16*)(ws + 12976128);          // 14,155,776  (B,HW,192)
    bf16* f_hwc   = (bf16*)(ws + 27131904);          //  2,359,296  (B,HW,32)
    int4* meta    = (int4*)(ws + 29491200);          //  7,667,712  (B,13,HW) int4
    bf16* W1b     = (bf16*)(ws + 37158912);          //     43,008  (32,672)
    bf16* W2b     = (bf16*)(ws + 37201920);          //     18,432  (32,288)
    bf16* Wi      = (bf16*)(ws + 37220352);          //     36,864  (192,96)
    bf16* Wb      = (bf16*)(ws + 37257216);          //    319,488  (192,832)

    k_prep  <<<dim3(816),        256, 0, stream>>>(fw1, fw2, i2h_w, ret_w,
                                                   W1b, W2b, Wi, Wb);
    k_packx <<<dim3(144, Bn*Sn), 256, 0, stream>>>(inputs, x_hwc);
    k_packh0<<<dim3(144, Bn),    256, 0, stream>>>(states, h_hwcA);

    bf16* h_cur = h_hwcA;
    bf16* h_nxt = h_hwcB;
    for (int t = 0; t < Sn; ++t) {
        k_front    <<<dim3(96, Bn),  384, 0, stream>>>(x_hwc, h_cur, Wi, i2h_b,
                                                       W1b, fb1, i2h_hwc, f_hwc, t);
        k_conv2meta<<<dim3(96, Bn),  384, 0, stream>>>(f_hwc, W2b, fb2, meta);
        k_fused    <<<dim3(288, Bn), 256, 0, stream>>>(meta, h_cur, Wb, ret_b,
                                                       i2h_hwc, h_nxt, out, t);
        bf16* tmp = h_cur; h_cur = h_nxt; h_nxt = tmp;
    }
}